// Round 3
// baseline (564.200 us; speedup 1.0000x reference)
//
#include <hip/hip_runtime.h>
#include <hip/hip_bf16.h>
#include <stdint.h>

typedef __attribute__((ext_vector_type(8)))  short   short8;
typedef __attribute__((ext_vector_type(16))) float   floatx16;
typedef __attribute__((ext_vector_type(4)))  float   floatx4;

#define B_    64
#define CIN   64
#define COUT  128
#define T_    300
#define V_    25
#define NRED  (B_ * T_ * V_)     // 480000 elements per channel
#define NSLOTS 32
#define NT    12                 // t's per block; 300/12 = 25 chunks
#define EPS   1e-5f

// ws layout (bytes):
//   [0,     16384)  psum : 32*128 f32 partial sums
//   [16384, 32768)  psq  : 32*128 f32 partial sum-of-squares

__device__ __forceinline__ uint32_t pk2(float a, float b) {
    union { __hip_bfloat162 h; uint32_t u; } c;
    c.h = __float22bfloat162_rn(make_float2(a, b));
    return c.u;
}

__device__ __forceinline__ floatx16 fzero16() {
    floatx16 z;
#pragma unroll
    for (int i = 0; i < 16; ++i) z[i] = 0.f;
    return z;
}

// Hᵀ C-layout -> B-fragment layout for the Yᵀ MFMA, via lane^32 half-wave swap.
// C-layout: lane holds HT[m=(r&3)+8*(r>>2)+4q][n=l&31].
// B-frag s: lane needs HT[k=16s+8q+j][n=l&31], j=0..7.  (verified permutation, R2)
__device__ __forceinline__ void cvt_hb(const floatx16 h, int q, short8 hb[2]) {
    uint32_t pk[8], pp[8];
#pragma unroll
    for (int i = 0; i < 8; ++i) pk[i] = pk2(h[2 * i], h[2 * i + 1]);
#pragma unroll
    for (int i = 0; i < 8; ++i) pp[i] = (uint32_t)__shfl_xor((int)pk[i], 32, 64);
#pragma unroll
    for (int s = 0; s < 2; ++s) {
        union { short8 sv; uint32_t u[4]; } F;
        F.u[0] = q ? pp[4 * s + 2] : pk[4 * s];
        F.u[1] = q ? pp[4 * s + 3] : pk[4 * s + 1];
        F.u[2] = q ? pk[4 * s + 2] : pp[4 * s];
        F.u[3] = q ? pk[4 * s + 3] : pp[4 * s + 1];
        hb[s] = F.sv;
    }
}

// Per-block fragment prep (L2-hot after first block, amortized over NT t's):
//  wf[kk]: Wᵀ B-frag  B[k=c=16kk+8q+j][n=o=32*wave+ln]  = W[o][c]   (float4 loads)
//  af[s] : adjᵀ A-frag A[m=w=ln][k=v=16s+8q+j]          = adj[v][w] (zero-padded)
__device__ __forceinline__ void build_const_frags(const float* __restrict__ W,
                                                  const float* __restrict__ adj,
                                                  int wave, int ln, int q,
                                                  short8 wf[4], short8 af[2]) {
    const float* wr = W + (32 * wave + ln) * CIN;
#pragma unroll
    for (int kk = 0; kk < 4; ++kk) {
        int c0 = 16 * kk + 8 * q;
        floatx4 a = *(const floatx4*)(wr + c0);
        floatx4 b = *(const floatx4*)(wr + c0 + 4);
        union { short8 sv; uint32_t u[4]; } F;
        F.u[0] = pk2(a[0], a[1]); F.u[1] = pk2(a[2], a[3]);
        F.u[2] = pk2(b[0], b[1]); F.u[3] = pk2(b[2], b[3]);
        wf[kk] = F.sv;
    }
#pragma unroll
    for (int s = 0; s < 2; ++s) {
        union { short8 sv; uint32_t u[4]; } F;
#pragma unroll
        for (int p = 0; p < 4; ++p) {
            int v0 = 16 * s + 8 * q + 2 * p;
            float e0 = (v0     < V_ && ln < V_) ? adj[v0 * V_ + ln]       : 0.f;
            float e1 = (v0 + 1 < V_ && ln < V_) ? adj[(v0 + 1) * V_ + ln] : 0.f;
            F.u[p] = pk2(e0, e1);
        }
        af[s] = F.sv;
    }
}

// Xᵀ A-frags for one t: lane holds X[c=16kk+8q+j][v=ln] — COALESCED over lanes.
// loff = vcl + q*8*7500 (per-lane); uniform part folds into the SGPR base.
__device__ __forceinline__ void build_xa(const float* __restrict__ x,
                                         int base_u, int loff, short8 xa[4]) {
#pragma unroll
    for (int kk = 0; kk < 4; ++kk) {
        union { short8 sv; uint32_t u[4]; } F;
#pragma unroll
        for (int p = 0; p < 4; ++p) {
            float e0 = x[base_u + (16 * kk + 2 * p) * (T_ * V_) + loff];
            float e1 = x[base_u + (16 * kk + 2 * p + 1) * (T_ * V_) + loff];
            F.u[p] = pk2(e0, e1);
        }
        xa[kk] = F.sv;
    }
}

// Yᵀ for one t: Hᵀ = Xᵀ·Wᵀ (K=c=64), convert, Yᵀ = adjᵀ·Hᵀ (K=v=32).
// Yᵀ C-layout: lane -> channel o, regs -> w; rows w>=25 are exactly 0.
__device__ __forceinline__ floatx16 compute_yt(const short8 xa[4], const short8 wf[4],
                                               const short8 af[2], int q) {
    floatx16 h = fzero16();
#pragma unroll
    for (int kk = 0; kk < 4; ++kk)
        h = __builtin_amdgcn_mfma_f32_32x32x16_bf16(xa[kk], wf[kk], h, 0, 0, 0);
    short8 hb[2];
    cvt_hb(h, q, hb);
    floatx16 y = fzero16();
#pragma unroll
    for (int s = 0; s < 2; ++s)
        y = __builtin_amdgcn_mfma_f32_32x32x16_bf16(af[s], hb[s], y, 0, 0, 0);
    return y;
}

// ---- pass 1: per-channel sum / sumsq partials ------------------------------
// Block 256 = 4 waves; wave w owns channels 32w..32w+31 (one per lane).
// Grid (25, 64): NT consecutive t per block, b = blockIdx.y. No LDS/barriers.
__global__ __launch_bounds__(256, 3) void pass1_kernel(
    const float* __restrict__ x, const float* __restrict__ adj,
    const float* __restrict__ W,
    float* __restrict__ psum, float* __restrict__ psq)
{
    const int tid  = threadIdx.x;
    const int wave = tid >> 6;
    const int lane = tid & 63;
    const int q    = lane >> 5;
    const int ln   = lane & 31;
    const int b    = blockIdx.y;
    const int tbase = blockIdx.x * NT;

    short8 wf[4], af[2];
    build_const_frags(W, adj, wave, ln, q, wf, af);

    const int vcl  = ln < V_ ? ln : V_ - 1;           // clamp: garbage lanes feed zero adj rows
    const int loff = vcl + q * 8 * (T_ * V_);

    float sum = 0.f, sq = 0.f;
    for (int i = 0; i < NT; ++i) {
        const int t = tbase + i;
        const int base_u = b * (CIN * T_ * V_) + t * V_;
        short8 xa[4];
        build_xa(x, base_u, loff, xa);
        floatx16 y = compute_yt(xa, wf, af, q);
#pragma unroll
        for (int r = 0; r < 16; ++r) { sum += y[r]; sq += y[r] * y[r]; }
    }

    // channel o=32*wave+ln lives in lanes l and l+32 (different w halves)
    sum += __shfl_xor(sum, 32, 64);
    sq  += __shfl_xor(sq,  32, 64);
    if (q == 0) {
        int slot = (blockIdx.y * 25 + blockIdx.x) & (NSLOTS - 1);
        atomicAdd(&psum[slot * COUT + 32 * wave + ln], sum);
        atomicAdd(&psq [slot * COUT + 32 * wave + ln], sq);
    }
}

// ---- pass 2: recompute Yᵀ, fold stats, normalize + relu, store -------------
__global__ __launch_bounds__(256, 3) void pass2_kernel(
    const float* __restrict__ x, const float* __restrict__ adj,
    const float* __restrict__ W,
    const float* __restrict__ gamma, const float* __restrict__ beta,
    const float* __restrict__ psum, const float* __restrict__ psq,
    float* __restrict__ out)
{
    const int tid  = threadIdx.x;
    const int wave = tid >> 6;
    const int lane = tid & 63;
    const int q    = lane >> 5;
    const int ln   = lane & 31;
    const int b    = blockIdx.y;
    const int tbase = blockIdx.x * NT;
    const int o_l  = 32 * wave + ln;

    short8 wf[4], af[2];
    build_const_frags(W, adj, wave, ln, q, wf, af);

    // fold the 32 partial slots -> per-lane scale/shift (L2-hot, coalesced)
    float s = 0.f, ss = 0.f;
#pragma unroll 4
    for (int k = 0; k < NSLOTS; ++k) {
        s  += psum[k * COUT + o_l];
        ss += psq [k * COUT + o_l];
    }
    const float mean = s / (float)NRED;
    const float var  = ss / (float)NRED - mean * mean;
    const float inv  = rsqrtf(var + EPS);
    const float sc   = gamma[o_l] * inv;
    const float sh   = beta[o_l] - mean * sc;

    const int vcl  = ln < V_ ? ln : V_ - 1;
    const int loff = vcl + q * 8 * (T_ * V_);
    const int po   = o_l * (T_ * V_) + 4 * q;         // per-lane out offset (+w base)

    for (int i = 0; i < NT; ++i) {
        const int t = tbase + i;
        const int base_u = b * (CIN * T_ * V_) + t * V_;
        short8 xa[4];
        build_xa(x, base_u, loff, xa);
        floatx16 y = compute_yt(xa, wf, af, q);

        float* ob = out + (size_t)(b * (COUT * T_ * V_) + t * V_);
        // regs r=4g+i map w = 4q + 8g + i : contiguous 4-float runs per g
#pragma unroll
        for (int g = 0; g < 3; ++g) {
            float tmp[4];
#pragma unroll
            for (int j = 0; j < 4; ++j) {
                float v = sc * y[4 * g + j] + sh;
                tmp[j] = v > 0.f ? v : 0.f;
            }
            __builtin_memcpy(&ob[po + 8 * g], tmp, 16);  // 4B-aligned 16B store
        }
        if (q == 0) {                                    // w = 24 (g=3, j=0)
            float v = sc * y[12] + sh;
            ob[po + 24] = v > 0.f ? v : 0.f;
        }
    }
}

extern "C" void kernel_launch(void* const* d_in, const int* in_sizes, int n_in,
                              void* d_out, int out_size, void* d_ws, size_t ws_size,
                              hipStream_t stream) {
    const float* x     = (const float*)d_in[0];
    const float* adj   = (const float*)d_in[1];
    const float* W     = (const float*)d_in[2];
    // d_in[3] = conv bias: cancelled exactly by training-mode BatchNorm -> unused
    const float* gamma = (const float*)d_in[4];
    const float* beta  = (const float*)d_in[5];
    float* out = (float*)d_out;

    float* psum = (float*)d_ws;
    float* psq  = (float*)((char*)d_ws + NSLOTS * COUT * sizeof(float));

    hipMemsetAsync(psum, 0, 2 * NSLOTS * COUT * sizeof(float), stream);

    dim3 grid(T_ / NT, B_);
    pass1_kernel<<<grid, 256, 0, stream>>>(x, adj, W, psum, psq);
    pass2_kernel<<<grid, 256, 0, stream>>>(x, adj, W, gamma, beta, psum, psq, out);
}

// Round 4
// 457.383 us; speedup vs baseline: 1.2335x; 1.2335x over previous
//
#include <hip/hip_runtime.h>
#include <hip/hip_bf16.h>
#include <stdint.h>

typedef __attribute__((ext_vector_type(8)))  short   short8;
typedef __attribute__((ext_vector_type(16))) float   floatx16;
typedef __attribute__((ext_vector_type(4)))  float   floatx4;

#define B_    64
#define CIN   64
#define COUT  128
#define T_    300
#define V_    25
#define NRED  (B_ * T_ * V_)     // 480000 elements per channel
#define NSLOTS 32
#define NT    12                 // t's per block; 300/12 = 25 chunks; groups of 4
#define EPS   1e-5f

__device__ __forceinline__ uint32_t pk2(float a, float b) {
    union { __hip_bfloat162 h; uint32_t u; } c;
    c.h = __float22bfloat162_rn(make_float2(a, b));
    return c.u;
}

__device__ __forceinline__ floatx16 fzero16() {
    floatx16 z;
#pragma unroll
    for (int i = 0; i < 16; ++i) z[i] = 0.f;
    return z;
}

// magic division by 25, valid for 0 <= n < 2048
__device__ __forceinline__ int div25(int n) { return (n * 5243) >> 17; }

// Hᵀ C-layout -> B-fragment layout via lane^32 half-wave swap (verified R2/R3).
__device__ __forceinline__ void cvt_hb(const floatx16 h, int q, short8 hb[2]) {
    uint32_t pk[8], pp[8];
#pragma unroll
    for (int i = 0; i < 8; ++i) pk[i] = pk2(h[2 * i], h[2 * i + 1]);
#pragma unroll
    for (int i = 0; i < 8; ++i) pp[i] = (uint32_t)__shfl_xor((int)pk[i], 32, 64);
#pragma unroll
    for (int s = 0; s < 2; ++s) {
        union { short8 sv; uint32_t u[4]; } F;
        F.u[0] = q ? pp[4 * s + 2] : pk[4 * s];
        F.u[1] = q ? pp[4 * s + 3] : pk[4 * s + 1];
        F.u[2] = q ? pk[4 * s + 2] : pp[4 * s];
        F.u[3] = q ? pk[4 * s + 3] : pp[4 * s + 1];
        hb[s] = F.sv;
    }
}

// Per-block constant fragments (verified R3):
//  wf[kk]: Wᵀ B-frag  B[k=c=16kk+8q+j][n=o=32*wave+ln] = W[o][c]
//  af[s] : adjᵀ A-frag A[m=w=ln][k=v=16s+8q+j]         = adj[v][w] (zero-padded)
__device__ __forceinline__ void build_const_frags(const float* __restrict__ W,
                                                  const float* __restrict__ adj,
                                                  int wave, int ln, int q,
                                                  short8 wf[4], short8 af[2]) {
    const float* wr = W + (32 * wave + ln) * CIN;
#pragma unroll
    for (int kk = 0; kk < 4; ++kk) {
        int c0 = 16 * kk + 8 * q;
        floatx4 a = *(const floatx4*)(wr + c0);
        floatx4 b = *(const floatx4*)(wr + c0 + 4);
        union { short8 sv; uint32_t u[4]; } F;
        F.u[0] = pk2(a[0], a[1]); F.u[1] = pk2(a[2], a[3]);
        F.u[2] = pk2(b[0], b[1]); F.u[3] = pk2(b[2], b[3]);
        wf[kk] = F.sv;
    }
#pragma unroll
    for (int s = 0; s < 2; ++s) {
        union { short8 sv; uint32_t u[4]; } F;
#pragma unroll
        for (int p = 0; p < 4; ++p) {
            int v0 = 16 * s + 8 * q + 2 * p;
            float e0 = (v0     < V_ && ln < V_) ? adj[v0 * V_ + ln]       : 0.f;
            float e1 = (v0 + 1 < V_ && ln < V_) ? adj[(v0 + 1) * V_ + ln] : 0.f;
            F.u[p] = pk2(e0, e1);
        }
        af[s] = F.sv;
    }
}

// Cooperative stage of 4 t's of X (64 c-rows x 100 floats) into LDS.
// t4 % 4 == 0 -> every dwordx4 is 16B-aligned in global and LDS. 1600 chunks
// over 256 threads = 7 insts/thread (last partially masked).
__device__ __forceinline__ void stage_x(const float* __restrict__ xb, int t4,
                                        float* __restrict__ ldsx, int tid) {
#pragma unroll
    for (int i = 0; i < 7; ++i) {
        int cid = i * 256 + tid;
        if (i < 6 || tid < 64) {
            int c  = div25(cid);
            int ch = cid - 25 * c;
            *(floatx4*)&ldsx[c * 100 + 4 * ch] =
                *(const floatx4*)(xb + c * 7500 + t4 * 25 + 4 * ch);
        }
    }
}

// Xᵀ A-frags from staged LDS: lane holds X[c=16kk+8q+2p(+1)][v=ln] for t=t4+tloc.
__device__ __forceinline__ void build_xa_lds(const float* __restrict__ ldsx,
                                             int tloc, int vcl, int q, short8 xa[4]) {
    const float* base = ldsx + tloc * 25 + vcl;
#pragma unroll
    for (int kk = 0; kk < 4; ++kk) {
        union { short8 sv; uint32_t u[4]; } F;
#pragma unroll
        for (int p = 0; p < 4; ++p) {
            int c0 = 16 * kk + 8 * q + 2 * p;
            F.u[p] = pk2(base[c0 * 100], base[(c0 + 1) * 100]);
        }
        xa[kk] = F.sv;
    }
}

// Yᵀ for one t (verified R3): Hᵀ = Xᵀ·Wᵀ (K=64), cvt, Yᵀ = adjᵀ·Hᵀ (K=32).
// C-layout: lane -> channel o (col), regs -> w rows; w>=25 exactly 0.
__device__ __forceinline__ floatx16 compute_yt(const short8 xa[4], const short8 wf[4],
                                               const short8 af[2], int q) {
    floatx16 h = fzero16();
#pragma unroll
    for (int kk = 0; kk < 4; ++kk)
        h = __builtin_amdgcn_mfma_f32_32x32x16_bf16(xa[kk], wf[kk], h, 0, 0, 0);
    short8 hb[2];
    cvt_hb(h, q, hb);
    floatx16 y = fzero16();
#pragma unroll
    for (int s = 0; s < 2; ++s)
        y = __builtin_amdgcn_mfma_f32_32x32x16_bf16(af[s], hb[s], y, 0, 0, 0);
    return y;
}

// ---- pass 1: per-channel sum / sumsq partials ------------------------------
// Grid (25, 64), block 256 = 4 waves; wave w owns o-tile w. LDS = staged x only.
__global__ __launch_bounds__(256, 3) void pass1_kernel(
    const float* __restrict__ x, const float* __restrict__ adj,
    const float* __restrict__ W,
    float* __restrict__ psum, float* __restrict__ psq)
{
    __shared__ __attribute__((aligned(16))) float ldsx[6400];

    const int tid  = threadIdx.x;
    const int wave = tid >> 6;
    const int lane = tid & 63;
    const int q    = lane >> 5;
    const int ln   = lane & 31;
    const int b    = blockIdx.y;
    const int tbase = blockIdx.x * NT;

    short8 wf[4], af[2];
    build_const_frags(W, adj, wave, ln, q, wf, af);
    const int vcl = ln < V_ ? ln : V_ - 1;   // clamp: garbage rows killed by af zero-pad
    const float* xb = x + (size_t)b * (CIN * T_ * V_);

    float sum = 0.f, sq = 0.f;
    for (int g = 0; g < NT / 4; ++g) {
        const int t4 = tbase + 4 * g;
        stage_x(xb, t4, ldsx, tid);
        __syncthreads();
#pragma unroll
        for (int tloc = 0; tloc < 4; ++tloc) {
            short8 xa[4];
            build_xa_lds(ldsx, tloc, vcl, q, xa);
            floatx16 y = compute_yt(xa, wf, af, q);
#pragma unroll
            for (int r = 0; r < 16; ++r) { sum += y[r]; sq += y[r] * y[r]; }
        }
        __syncthreads();
    }

    // channel o=32*wave+ln lives in lanes l and l^32
    sum += __shfl_xor(sum, 32, 64);
    sq  += __shfl_xor(sq,  32, 64);
    if (q == 0) {
        int slot = (blockIdx.y * 25 + blockIdx.x) & (NSLOTS - 1);
        atomicAdd(&psum[slot * COUT + 32 * wave + ln], sum);
        atomicAdd(&psq [slot * COUT + 32 * wave + ln], sq);
    }
}

// ---- pass 2: recompute Yᵀ, normalize + relu, LDS-stage, coalesced flush ----
__global__ __launch_bounds__(256, 2) void pass2_kernel(
    const float* __restrict__ x, const float* __restrict__ adj,
    const float* __restrict__ W,
    const float* __restrict__ gamma, const float* __restrict__ beta,
    const float* __restrict__ psum, const float* __restrict__ psq,
    float* __restrict__ out)
{
    __shared__ __attribute__((aligned(16))) float ldsx[6400];
    __shared__ __attribute__((aligned(16))) float ldso[4][3200];

    const int tid  = threadIdx.x;
    const int wave = tid >> 6;
    const int lane = tid & 63;
    const int q    = lane >> 5;
    const int ln   = lane & 31;
    const int b    = blockIdx.y;
    const int tbase = blockIdx.x * NT;
    const int o_l  = 32 * wave + ln;

    short8 wf[4], af[2];
    build_const_frags(W, adj, wave, ln, q, wf, af);

    // fold the 32 partial slots -> per-lane scale/shift
    float s = 0.f, ss = 0.f;
#pragma unroll 4
    for (int k = 0; k < NSLOTS; ++k) {
        s  += psum[k * COUT + o_l];
        ss += psq [k * COUT + o_l];
    }
    const float mean = s / (float)NRED;
    const float var  = ss / (float)NRED - mean * mean;
    const float inv  = rsqrtf(var + EPS);
    const float sc   = gamma[o_l] * inv;
    const float sh   = beta[o_l] - mean * sc;

    const int vcl = ln < V_ ? ln : V_ - 1;
    const float* xb = x + (size_t)b * (CIN * T_ * V_);
    float* const ob = out + (size_t)(b * COUT + 32 * wave) * (T_ * V_);

    for (int g = 0; g < NT / 4; ++g) {
        const int t4 = tbase + 4 * g;
        stage_x(xb, t4, ldsx, tid);
        __syncthreads();

        float* const ow0 = &ldso[wave][ln * 100];
#pragma unroll
        for (int tloc = 0; tloc < 4; ++tloc) {
            short8 xa[4];
            build_xa_lds(ldsx, tloc, vcl, q, xa);
            floatx16 y = compute_yt(xa, wf, af, q);
            // stage relu'd values: [o=ln][tloc*25 + w], w = 4q + 8g2 + j
            float* ow = ow0 + tloc * 25 + 4 * q;
#pragma unroll
            for (int g2 = 0; g2 < 3; ++g2) {
#pragma unroll
                for (int j = 0; j < 4; ++j) {
                    float v = sc * y[4 * g2 + j] + sh;
                    ow[8 * g2 + j] = v > 0.f ? v : 0.f;
                }
            }
            if (q == 0) {                      // w = 24  (reg 12)
                float v = sc * y[12] + sh;
                ow0[tloc * 25 + 24] = v > 0.f ? v : 0.f;
            }
        }

        // flush this wave's 32o x 100 floats: 13 coalesced 16B-aligned dwordx4
#pragma unroll
        for (int f = 0; f < 13; ++f) {
            int cid = f * 64 + lane;
            if (f < 12 || lane < 32) {
                int o = div25(cid);
                int c = cid - 25 * o;
                floatx4 v = *(const floatx4*)&ldso[wave][o * 100 + 4 * c];
                *(floatx4*)(ob + (size_t)o * (T_ * V_) + t4 * 25 + 4 * c) = v;
            }
        }
        __syncthreads();
    }
}

// ---- stats are folded inside pass2; nothing else needed --------------------

extern "C" void kernel_launch(void* const* d_in, const int* in_sizes, int n_in,
                              void* d_out, int out_size, void* d_ws, size_t ws_size,
                              hipStream_t stream) {
    const float* x     = (const float*)d_in[0];
    const float* adj   = (const float*)d_in[1];
    const float* W     = (const float*)d_in[2];
    // d_in[3] = conv bias: cancelled exactly by training-mode BatchNorm -> unused
    const float* gamma = (const float*)d_in[4];
    const float* beta  = (const float*)d_in[5];
    float* out = (float*)d_out;

    float* psum = (float*)d_ws;
    float* psq  = (float*)((char*)d_ws + NSLOTS * COUT * sizeof(float));

    hipMemsetAsync(psum, 0, 2 * NSLOTS * COUT * sizeof(float), stream);

    dim3 grid(T_ / NT, B_);
    pass1_kernel<<<grid, 256, 0, stream>>>(x, adj, W, psum, psq);
    pass2_kernel<<<grid, 256, 0, stream>>>(x, adj, W, gamma, beta, psum, psq, out);
}